// Round 9
// baseline (737.609 us; speedup 1.0000x reference)
//
#include <hip/hip_runtime.h>
#include <stdint.h>

#define M_ROWS 8192
#define K_DIM  4096
#define N_DIM  11008
#define KSTEPS (K_DIM / 64)      // 64 K-tiles of BK=64

// ---- 256x256 tile, 4 waves (2M x 2N), per-wave output 128x128 ----
#define BM 256
#define BN 256
#define MBLKS (M_ROWS / BM)      // 32
#define NBLKS (N_DIM / BN)       // 43
#define NWG   (MBLKS * NBLKS)    // 1376

typedef __attribute__((ext_vector_type(4))) float          f32x4;
typedef __attribute__((ext_vector_type(8))) __bf16         bf16x8;
typedef __attribute__((ext_vector_type(4))) int            i32x4;
typedef __attribute__((ext_vector_type(8))) unsigned short u16x8;

__constant__ float NF4_TBL[16] = {
    -1.0f, -0.6961928009986877f, -0.5250730514526367f, -0.39491748809814453f,
    -0.28444138169288635f, -0.18477343022823334f, -0.10644006729125977f,
    -0.029167551919817924f, 0.0f, 0.07958029955625534f, 0.16093020141124725f,
    0.24611230194568634f, 0.33791524171829224f, 0.44070982933044434f,
    0.5626170039176941f, 0.7229568362236023f};

__device__ __forceinline__ unsigned short f2bf(float f) {
  uint32_t u = __float_as_uint(f);
  u += 0x7fffu + ((u >> 16) & 1u);   // RNE
  return (unsigned short)(u >> 16);
}

__device__ __forceinline__ void gload_lds16(const void* g, const void* l) {
  __builtin_amdgcn_global_load_lds(
      (const __attribute__((address_space(1))) void*)(uintptr_t)g,
      (__attribute__((address_space(3))) void*)(uint32_t)(uintptr_t)l,
      16, 0, 0);
}

// ---------------- prep 1: x fp32 -> bf16 ----------------
__global__ void convert_x_kernel(const float* __restrict__ x,
                                 unsigned short* __restrict__ xb) {
  const long n8 = (long)M_ROWS * K_DIM / 8;
  for (long t = (long)blockIdx.x * blockDim.x + threadIdx.x; t < n8;
       t += (long)gridDim.x * blockDim.x) {
    const float* p = x + t * 8;
    f32x4 v0 = *(const f32x4*)p;
    f32x4 v1 = *(const f32x4*)(p + 4);
    u16x8 o;
    o[0] = f2bf(v0[0]); o[1] = f2bf(v0[1]); o[2] = f2bf(v0[2]); o[3] = f2bf(v0[3]);
    o[4] = f2bf(v1[0]); o[5] = f2bf(v1[1]); o[6] = f2bf(v1[2]); o[7] = f2bf(v1[3]);
    *(u16x8*)(xb + t * 8) = o;
  }
}

// ---------------- prep 2: NF4 dequant W -> bf16 ----------------
__global__ void dequant_w_kernel(const int* __restrict__ qw,
                                 const int* __restrict__ qs,
                                 const float* __restrict__ qf,
                                 const float* __restrict__ mean,
                                 unsigned short* __restrict__ wb) {
  __shared__ float tbl[16];
  if (threadIdx.x < 16) tbl[threadIdx.x] = NF4_TBL[threadIdx.x];
  __syncthreads();
  const float mu = mean[0];
  const long n8 = (long)N_DIM * K_DIM / 8;
  for (long t = (long)blockIdx.x * blockDim.x + threadIdx.x; t < n8;
       t += (long)gridDim.x * blockDim.x) {
    long f = t * 8;
    int  g = (int)(f >> 6);
    float s = (float)qs[g] / qf[g >> 8] + mu;
    i32x4 q0 = *(const i32x4*)(qw + f);
    i32x4 q1 = *(const i32x4*)(qw + f + 4);
    u16x8 o;
    o[0] = f2bf(tbl[q0[0]] * s); o[1] = f2bf(tbl[q0[1]] * s);
    o[2] = f2bf(tbl[q0[2]] * s); o[3] = f2bf(tbl[q0[3]] * s);
    o[4] = f2bf(tbl[q1[0]] * s); o[5] = f2bf(tbl[q1[1]] * s);
    o[6] = f2bf(tbl[q1[2]] * s); o[7] = f2bf(tbl[q1[3]] * s);
    *(u16x8*)(wb + f) = o;
  }
}

// ---------------- 256x256, 4-wave fat-tile bf16 GEMM:  C = A * B^T ----------------
// R7/R8 skeleton (A triple buffer slot t%3 at 0/32768/65536, B double buffer at
// 98304+par*32768; ONE barrier + ONE counted vmcnt per K-tile; T2 swizzle; R7
// supertile map). NEW: 4 waves (2x2), per-wave 128x128 output -> LDS read
// traffic drops 192KB -> 128KB per tile (traffic = sum(Mw+Nw)*BK), and each
// wave carries 128 MFMA per 32 ds_reads (2x the MFMA cover per read).
// Registers: acc 256 + bq 64 + af 32 ~= 360 of 512 (1 wave/SIMD; LDS already
// caps at 1 block/CU so prior 2-wave/SIMD config wasted half the reg file).
// Staging: 16 gloads/wave/tile (B(t+1) at c0/c1, A(t+2) at c2/c3); boundary
// vmcnt(8) allows only A(t+2)'s 8 in flight; ledger as before.
#define STG(GP, LB)                                                              \
  gload_lds16((GP) + (long)srow * K_DIM + scol,                                  \
              &LDSbuf[(LB) + wid * 1024]);                                       \
  gload_lds16((GP) + (long)(srow + 32) * K_DIM + scol,                           \
              &LDSbuf[(LB) + wid * 1024 + 4096]);                                \
  gload_lds16((GP) + (long)(srow + 64) * K_DIM + scol,                           \
              &LDSbuf[(LB) + wid * 1024 + 8192]);                                \
  gload_lds16((GP) + (long)(srow + 96) * K_DIM + scol,                           \
              &LDSbuf[(LB) + wid * 1024 + 12288]);

#define SB __builtin_amdgcn_sched_barrier(0)

// read one m-pair (2 frags x 2 halves) from A slot SA
#define RD_A2(DST, MB, SA)                                                        \
  DST[0][0] = *(const bf16x8*)&LDSbuf[(SA) + aoff + (MB) * 2048 + kswz0];         \
  DST[0][1] = *(const bf16x8*)&LDSbuf[(SA) + aoff + (MB) * 2048 + kswz1];         \
  DST[1][0] = *(const bf16x8*)&LDSbuf[(SA) + aoff + ((MB) + 1) * 2048 + kswz0];   \
  DST[1][1] = *(const bf16x8*)&LDSbuf[(SA) + aoff + ((MB) + 1) * 2048 + kswz1];

// read one n-quad of B into bq[N0..N0+3]
#define RD_B4(N0, CB)                                                             \
  bq[(N0) + 0][0] = *(const bf16x8*)&LDSbuf[(CB) + boff + ((N0) + 0) * 2048 + kswz0]; \
  bq[(N0) + 0][1] = *(const bf16x8*)&LDSbuf[(CB) + boff + ((N0) + 0) * 2048 + kswz1]; \
  bq[(N0) + 1][0] = *(const bf16x8*)&LDSbuf[(CB) + boff + ((N0) + 1) * 2048 + kswz0]; \
  bq[(N0) + 1][1] = *(const bf16x8*)&LDSbuf[(CB) + boff + ((N0) + 1) * 2048 + kswz1]; \
  bq[(N0) + 2][0] = *(const bf16x8*)&LDSbuf[(CB) + boff + ((N0) + 2) * 2048 + kswz0]; \
  bq[(N0) + 2][1] = *(const bf16x8*)&LDSbuf[(CB) + boff + ((N0) + 2) * 2048 + kswz1]; \
  bq[(N0) + 3][0] = *(const bf16x8*)&LDSbuf[(CB) + boff + ((N0) + 3) * 2048 + kswz0]; \
  bq[(N0) + 3][1] = *(const bf16x8*)&LDSbuf[(CB) + boff + ((N0) + 3) * 2048 + kswz1];

#define MFP(MI, AF, AI, NI)                                                       \
  acc[MI][NI] = __builtin_amdgcn_mfma_f32_16x16x32_bf16(AF[AI][0], bq[NI][0], acc[MI][NI], 0, 0, 0); \
  acc[MI][NI] = __builtin_amdgcn_mfma_f32_16x16x32_bf16(AF[AI][1], bq[NI][1], acc[MI][NI], 0, 0, 0);

// one cluster: m-pair (MB, MB+1 via AF) x n-quad (N0..N0+3) = 16 MFMA
#define CL(MB, AF, N0)                                                            \
  __builtin_amdgcn_s_setprio(1);                                                  \
  MFP((MB) + 0, AF, 0, (N0) + 0) MFP((MB) + 1, AF, 1, (N0) + 0)                   \
  MFP((MB) + 0, AF, 0, (N0) + 1) MFP((MB) + 1, AF, 1, (N0) + 1)                   \
  MFP((MB) + 0, AF, 0, (N0) + 2) MFP((MB) + 1, AF, 1, (N0) + 2)                   \
  MFP((MB) + 0, AF, 0, (N0) + 3) MFP((MB) + 1, AF, 1, (N0) + 3)                   \
  __builtin_amdgcn_s_setprio(0);

__global__ __launch_bounds__(256, 1) void gemm_pipe(
    const unsigned short* __restrict__ xb, const unsigned short* __restrict__ wb,
    float* __restrict__ C) {
  __align__(16) __shared__ unsigned char LDSbuf[163840];   // 96K A(3) + 64K B(2)

  const int tid = threadIdx.x;
  const int wid = tid >> 6, lane = tid & 63;
  const int wr = wid >> 1, wc = wid & 1;
  const int r16 = lane & 15, hi = lane >> 4;

  // ---- supertile mapping: 8mb x 4nb concurrent per XCD (R7-proven) ----
  const int p = ((int)blockIdx.x & 7) * (NWG / 8) + ((int)blockIdx.x >> 3);
  int mb, nb;
  if (p < 1280) {                 // 10 full nbg x 4 mbg x 32
    const int nbg = p >> 7;
    const int rem = p & 127;
    const int mbg = rem >> 5;
    const int s   = rem & 31;
    mb = mbg * 8 + (s & 7);
    nb = nbg * 4 + (s >> 3);
  } else {                        // ragged tail: nb 40..42, 4 mbg x 24
    const int q   = p - 1280;
    const int mbg = q / 24;
    const int s   = q % 24;
    mb = mbg * 8 + (s & 7);
    nb = 40 + (s >> 3);
  }
  const long m0g = (long)mb * BM, n0g = (long)nb * BN;

  // staging coords (per lane); T2: linear LDS dest, inverse-swizzled source.
  // 4 waves cover 32 rows per gload round; 4 rounds = 128-row half-tile.
  const int srow = wid * 8 + (lane >> 3);
  const int scol = ((lane & 7) ^ (lane >> 3)) * 8;

  // ds_read coords (T2 swizzle on read)
  const int aoff = (wr * 128 + r16) * 128;
  const int boff = (wc * 128 + r16) * 128;
  const int kswz0 = ((hi ^ (r16 & 7)) << 4);
  const int kswz1 = kswz0 ^ 64;

  // ---- prologue: A(0)->slot0, B(0)->par0, A(1)->slot1; wait all but A(1) ----
  STG(xb + m0g * K_DIM,              0);
  STG(xb + (m0g + 128) * K_DIM,      16384);
  STG(wb + n0g * K_DIM,              98304);
  STG(wb + (n0g + 128) * K_DIM,      98304 + 16384);
  STG(xb + m0g * K_DIM + 64,         32768);
  STG(xb + (m0g + 128) * K_DIM + 64, 32768 + 16384);
  asm volatile("s_waitcnt vmcnt(8)");
  __builtin_amdgcn_sched_barrier(0);
  __builtin_amdgcn_s_barrier();

  bf16x8 af_a[2][2], af_b[2][2], bq[8][2];
  f32x4 acc[8][8] = {};

  int sAr = 0, sAn = 32768, sAs = 65536;   // A slots: read(t), read(t+1), stage(t+2)

  for (int t = 0; t < KSTEPS; ++t) {
    const int cur = t & 1;
    const int cB = 98304 + cur * 32768;
    const int nB = 98304 + (cur ^ 1) * 32768;
    const long kB = (long)((t + 1 < KSTEPS ? t + 1 : KSTEPS - 1) * 64);
    const long kA = (long)((t + 2 < KSTEPS ? t + 2 : KSTEPS - 1) * 64);

    // ---- pre: A m01, B n0-3 ----
    RD_A2(af_a, 0, sAr);
    RD_B4(0, cB);
    SB;
    // ---- c0: read B n4-7; stage B(t+1)h0; MFMA m01 x n0-3 ----
    RD_B4(4, cB);
    STG(wb + n0g * K_DIM + kB, nB);
    CL(0, af_a, 0)
    SB;
    // ---- c1: read A m23; stage B(t+1)h1; MFMA m01 x n4-7 ----
    RD_A2(af_b, 2, sAr);
    STG(wb + (n0g + 128) * K_DIM + kB, nB + 16384);
    CL(0, af_a, 4)
    SB;
    // ---- c2: read A m45; stage A(t+2)h0; MFMA m23 x n0-3 ----
    RD_A2(af_a, 4, sAr);
    STG(xb + m0g * K_DIM + kA, sAs);
    CL(2, af_b, 0)
    SB;
    // ---- c3: stage A(t+2)h1; MFMA m23 x n4-7 ----
    STG(xb + (m0g + 128) * K_DIM + kA, sAs + 16384);
    CL(2, af_b, 4)
    SB;
    // ---- c4: read A m67; MFMA m45 x n0-3 ----
    RD_A2(af_b, 6, sAr);
    CL(4, af_a, 0)
    SB;
    // ---- c5: MFMA m45 x n4-7 ----
    CL(4, af_a, 4)
    SB;
    // ---- c6: MFMA m67 x n0-3 ----
    CL(6, af_b, 0)
    SB;
    // ---- c7: MFMA m67 x n4-7 ----
    CL(6, af_b, 4)
    // ---- tile boundary: ONE counted vmcnt + ONE barrier ----
    asm volatile("s_waitcnt vmcnt(8)");   // only A(t+2)'s 8 stages may remain
    __builtin_amdgcn_sched_barrier(0);
    __builtin_amdgcn_s_barrier();
    __builtin_amdgcn_sched_barrier(0);

    int tmp = sAr; sAr = sAn; sAn = sAs; sAs = tmp;   // rotate A slots
  }

  // ---- epilogue: C/D layout col=lane&15, row=hi*4+reg; nontemporal ----
  const long crow = m0g + wr * 128 + hi * 4;
  const long ccol = n0g + wc * 128 + r16;
#pragma unroll
  for (int m = 0; m < 8; ++m)
#pragma unroll
    for (int n = 0; n < 8; ++n)
#pragma unroll
      for (int r = 0; r < 4; ++r)
        __builtin_nontemporal_store(
            acc[m][n][r], &C[(crow + m * 16 + r) * N_DIM + ccol + n * 16]);
}

// ---------------- fallback (no workspace): fused 128^2 kernel ----------------
__global__ __launch_bounds__(256) void gemm_fallback(
    const float* __restrict__ Xf, const int* __restrict__ qw,
    const int* __restrict__ qs, const float* __restrict__ qf,
    const float* __restrict__ meanp, float* __restrict__ C) {
  __shared__ unsigned short As[128 * 64];
  __shared__ unsigned short Bs[128 * 64];
  __shared__ float tbl[16];
  const int tid = threadIdx.x;
  if (tid < 16) tbl[tid] = NF4_TBL[tid];
  const float mu = meanp[0];
  const int nwg = (M_ROWS / 128) * (N_DIM / 128);
  const int wg = ((int)blockIdx.x & 7) * (nwg / 8) + ((int)blockIdx.x >> 3);
  const int mbf = wg % (M_ROWS / 128), nbf = wg / (M_ROWS / 128);
  const int m0 = mbf * 128, n0 = nbf * 128;
  const int wid = tid >> 6, lane = tid & 63;
  const int wrf = wid >> 1, wcc = wid & 1;
  const int r16 = lane & 15, hi = lane >> 4;
  f32x4 acc[4][4] = {};
  for (int t = 0; t < KSTEPS; ++t) {
    const int k0 = t * 64;
    __syncthreads();
#pragma unroll
    for (int i = 0; i < 4; ++i) {
      int gi = i * 256 + tid;
      int row = gi >> 3, kq = (gi & 7) * 8;
      const float* px = Xf + (long)(m0 + row) * K_DIM + k0 + kq;
      f32x4 v0 = *(const f32x4*)px;
      f32x4 v1 = *(const f32x4*)(px + 4);
      u16x8 o;
      o[0] = f2bf(v0[0]); o[1] = f2bf(v0[1]); o[2] = f2bf(v0[2]); o[3] = f2bf(v0[3]);
      o[4] = f2bf(v1[0]); o[5] = f2bf(v1[1]); o[6] = f2bf(v1[2]); o[7] = f2bf(v1[3]);
      *(u16x8*)&As[row * 64 + kq] = o;
    }
#pragma unroll
    for (int i = 0; i < 4; ++i) {
      int gi = i * 256 + tid;
      int row = gi >> 3, kq = (gi & 7) * 8;
      const int* pq = qw + (long)(n0 + row) * K_DIM + k0 + kq;
      i32x4 q0 = *(const i32x4*)pq;
      i32x4 q1 = *(const i32x4*)(pq + 4);
      int g = (n0 + row) * (K_DIM / 64) + t;
      float s = (float)qs[g] / qf[g >> 8] + mu;
      u16x8 o;
      o[0] = f2bf(tbl[q0[0]] * s); o[1] = f2bf(tbl[q0[1]] * s);
      o[2] = f2bf(tbl[q0[2]] * s); o[3] = f2bf(tbl[q0[3]] * s);
      o[4] = f2bf(tbl[q1[0]] * s); o[5] = f2bf(tbl[q1[1]] * s);
      o[6] = f2bf(tbl[q1[2]] * s); o[7] = f2bf(tbl[q1[3]] * s);
      *(u16x8*)&Bs[row * 64 + kq] = o;
    }
    __syncthreads();
    bf16x8 afr[4][2], bfr[4][2];
#pragma unroll
    for (int i = 0; i < 4; ++i)
#pragma unroll
      for (int h = 0; h < 2; ++h) {
        afr[i][h] = *(const bf16x8*)&As[(wrf * 64 + i * 16 + r16) * 64 + h * 32 + hi * 8];
        bfr[i][h] = *(const bf16x8*)&Bs[(wcc * 64 + i * 16 + r16) * 64 + h * 32 + hi * 8];
      }
#pragma unroll
    for (int i = 0; i < 4; ++i)
#pragma unroll
      for (int j = 0; j < 4; ++j) {
        acc[i][j] = __builtin_amdgcn_mfma_f32_16x16x32_bf16(afr[i][0], bfr[j][0], acc[i][j], 0, 0, 0);
        acc[i][j] = __builtin_amdgcn_mfma_f32_16x16x32_bf16(afr[i][1], bfr[j][1], acc[i][j], 0, 0, 0);
      }
  }
  const int crow = m0 + wrf * 64 + hi * 4;
  const int ccol = n0 + wcc * 64 + r16;
#pragma unroll
  for (int i = 0; i < 4; ++i)
#pragma unroll
    for (int j = 0; j < 4; ++j)
#pragma unroll
      for (int r = 0; r < 4; ++r)
        C[(long)(crow + i * 16 + r) * N_DIM + (ccol + j * 16)] = acc[i][j][r];
}

extern "C" void kernel_launch(void* const* d_in, const int* in_sizes, int n_in,
                              void* d_out, int out_size, void* d_ws, size_t ws_size,
                              hipStream_t stream) {
  const float* x    = (const float*)d_in[0];
  const int*   qw   = (const int*)d_in[1];
  const int*   qs   = (const int*)d_in[2];
  const float* qf   = (const float*)d_in[3];
  const float* mean = (const float*)d_in[4];
  float* out = (float*)d_out;

  const size_t xb_bytes = (size_t)M_ROWS * K_DIM * 2;  // 64 MiB
  const size_t wb_bytes = (size_t)N_DIM * K_DIM * 2;   // 86 MiB

  if (ws_size >= xb_bytes + wb_bytes) {
    unsigned short* xb = (unsigned short*)d_ws;
    unsigned short* wb = (unsigned short*)((char*)d_ws + xb_bytes);
    convert_x_kernel<<<4096, 256, 0, stream>>>(x, xb);
    dequant_w_kernel<<<4096, 256, 0, stream>>>(qw, qs, qf, mean, wb);
    gemm_pipe<<<NWG, 256, 0, stream>>>(xb, wb, out);
  } else {
    gemm_fallback<<<(M_ROWS / 128) * (N_DIM / 128), 256, 0, stream>>>(
        x, qw, qs, qf, mean, out);
  }
}

// Round 10
// 703.442 us; speedup vs baseline: 1.0486x; 1.0486x over previous
//
#include <hip/hip_runtime.h>
#include <stdint.h>

#define M_ROWS 8192
#define K_DIM  4096
#define N_DIM  11008
#define KSTEPS (K_DIM / 64)      // 64 K-tiles of BK=64

// ---- 256x256 geometry, 8 waves (2M x 4N), per-wave output 128x64 ----
#define BM 256
#define BN 256
#define MBLKS (M_ROWS / BM)      // 32
#define NBLKS (N_DIM / BN)       // 43
#define NWG   (MBLKS * NBLKS)    // 1376

typedef __attribute__((ext_vector_type(4))) float          f32x4;
typedef __attribute__((ext_vector_type(8))) __bf16         bf16x8;
typedef __attribute__((ext_vector_type(4))) int            i32x4;
typedef __attribute__((ext_vector_type(8))) unsigned short u16x8;

__constant__ float NF4_TBL[16] = {
    -1.0f, -0.6961928009986877f, -0.5250730514526367f, -0.39491748809814453f,
    -0.28444138169288635f, -0.18477343022823334f, -0.10644006729125977f,
    -0.029167551919817924f, 0.0f, 0.07958029955625534f, 0.16093020141124725f,
    0.24611230194568634f, 0.33791524171829224f, 0.44070982933044434f,
    0.5626170039176941f, 0.7229568362236023f};

__device__ __forceinline__ unsigned short f2bf(float f) {
  uint32_t u = __float_as_uint(f);
  u += 0x7fffu + ((u >> 16) & 1u);   // RNE
  return (unsigned short)(u >> 16);
}

__device__ __forceinline__ void gload_lds16(const void* g, const void* l) {
  __builtin_amdgcn_global_load_lds(
      (const __attribute__((address_space(1))) void*)(uintptr_t)g,
      (__attribute__((address_space(3))) void*)(uint32_t)(uintptr_t)l,
      16, 0, 0);
}

// ---------------- prep 1: x fp32 -> bf16 ----------------
__global__ void convert_x_kernel(const float* __restrict__ x,
                                 unsigned short* __restrict__ xb) {
  const long n8 = (long)M_ROWS * K_DIM / 8;
  for (long t = (long)blockIdx.x * blockDim.x + threadIdx.x; t < n8;
       t += (long)gridDim.x * blockDim.x) {
    const float* p = x + t * 8;
    f32x4 v0 = *(const f32x4*)p;
    f32x4 v1 = *(const f32x4*)(p + 4);
    u16x8 o;
    o[0] = f2bf(v0[0]); o[1] = f2bf(v0[1]); o[2] = f2bf(v0[2]); o[3] = f2bf(v0[3]);
    o[4] = f2bf(v1[0]); o[5] = f2bf(v1[1]); o[6] = f2bf(v1[2]); o[7] = f2bf(v1[3]);
    *(u16x8*)(xb + t * 8) = o;
  }
}

// ---------------- prep 2: NF4 dequant W -> bf16 ----------------
__global__ void dequant_w_kernel(const int* __restrict__ qw,
                                 const int* __restrict__ qs,
                                 const float* __restrict__ qf,
                                 const float* __restrict__ mean,
                                 unsigned short* __restrict__ wb) {
  __shared__ float tbl[16];
  if (threadIdx.x < 16) tbl[threadIdx.x] = NF4_TBL[threadIdx.x];
  __syncthreads();
  const float mu = mean[0];
  const long n8 = (long)N_DIM * K_DIM / 8;
  for (long t = (long)blockIdx.x * blockDim.x + threadIdx.x; t < n8;
       t += (long)gridDim.x * blockDim.x) {
    long f = t * 8;
    int  g = (int)(f >> 6);
    float s = (float)qs[g] / qf[g >> 8] + mu;
    i32x4 q0 = *(const i32x4*)(qw + f);
    i32x4 q1 = *(const i32x4*)(qw + f + 4);
    u16x8 o;
    o[0] = f2bf(tbl[q0[0]] * s); o[1] = f2bf(tbl[q0[1]] * s);
    o[2] = f2bf(tbl[q0[2]] * s); o[3] = f2bf(tbl[q0[3]] * s);
    o[4] = f2bf(tbl[q1[0]] * s); o[5] = f2bf(tbl[q1[1]] * s);
    o[6] = f2bf(tbl[q1[2]] * s); o[7] = f2bf(tbl[q1[3]] * s);
    *(u16x8*)(wb + f) = o;
  }
}

// ---------------- 256x256 one-barrier-per-tile bf16 GEMM:  C = A * B^T ----------------
// R8 structure (A triple buffer slot t%3 at 0/32768/65536, B double buffer at
// 98304+par*32768; ONE barrier + ONE counted vmcnt(4) per K-tile; T2 swizzle;
// R7 supertile map; anti-phase cluster rotation for odd waves).
// NEW (m141 lesson applied): NO intra-tile sched_barriers and NO per-cluster
// setprio toggles -- the textual read/STG distribution seeds the schedule and
// the compiler is free to software-pipeline ds_reads into MFMA shadows and to
// separate dependent k0->k1 MFMA pairs. One setprio(1)/(0) pair per tile.
// Tile boundary keeps vmcnt(4)+sched_barrier+s_barrier (ledger unchanged:
// stage issue order B,B,A,A per wave is preserved -- gload_lds intrinsics are
// side-effecting and keep mutual order; asm volatile waits fence them).
#define STG(GP, LB)                                                              \
  gload_lds16((GP) + (long)srow * K_DIM + scol, &LDSbuf[(LB) + wid * 1024]);     \
  gload_lds16((GP) + (long)(64 + srow) * K_DIM + scol,                           \
              &LDSbuf[(LB) + 8192 + wid * 1024]);

#define RD_A2(DST, MB, SA)                                                        \
  DST[0][0] = *(const bf16x8*)&LDSbuf[(SA) + aoff + (MB) * 2048 + kswz0];         \
  DST[0][1] = *(const bf16x8*)&LDSbuf[(SA) + aoff + (MB) * 2048 + kswz1];         \
  DST[1][0] = *(const bf16x8*)&LDSbuf[(SA) + aoff + ((MB) + 1) * 2048 + kswz0];   \
  DST[1][1] = *(const bf16x8*)&LDSbuf[(SA) + aoff + ((MB) + 1) * 2048 + kswz1];

#define RD_B2(NB, CB)                                                             \
  bq[NB][0]     = *(const bf16x8*)&LDSbuf[(CB) + boff + (NB) * 2048 + kswz0];     \
  bq[NB][1]     = *(const bf16x8*)&LDSbuf[(CB) + boff + (NB) * 2048 + kswz1];     \
  bq[NB + 1][0] = *(const bf16x8*)&LDSbuf[(CB) + boff + ((NB) + 1) * 2048 + kswz0];\
  bq[NB + 1][1] = *(const bf16x8*)&LDSbuf[(CB) + boff + ((NB) + 1) * 2048 + kswz1];

#define MFP(MI, AF, AI, NI)                                                       \
  acc[MI][NI] = __builtin_amdgcn_mfma_f32_16x16x32_bf16(AF[AI][0], bq[NI][0], acc[MI][NI], 0, 0, 0); \
  acc[MI][NI] = __builtin_amdgcn_mfma_f32_16x16x32_bf16(AF[AI][1], bq[NI][1], acc[MI][NI], 0, 0, 0);

// full K-tile body, cluster ring rotated by BASE (0 for even waves, 4 for odd).
// No scheduling fences inside -- compiler pipelines freely.
#define TILE_BODY(BASE)                                                           \
    RD_A2(af_a, ((BASE) + 0) & 7, sAr);                                           \
    RD_B2(0, cB);                                                                 \
    RD_B2(2, cB);                                                                 \
    STG(wb + n0g * K_DIM + kB, nB);                                               \
    __builtin_amdgcn_s_setprio(1);                                                \
    MFP(((BASE) + 0) & 7, af_a, 0, 0) MFP(((BASE) + 1) & 7, af_a, 1, 0)           \
    MFP(((BASE) + 0) & 7, af_a, 0, 1) MFP(((BASE) + 1) & 7, af_a, 1, 1)           \
    RD_A2(af_b, ((BASE) + 2) & 7, sAr);                                           \
    STG(wb + (n0g + 128) * K_DIM + kB, nB + 16384);                               \
    MFP(((BASE) + 0) & 7, af_a, 0, 2) MFP(((BASE) + 1) & 7, af_a, 1, 2)           \
    MFP(((BASE) + 0) & 7, af_a, 0, 3) MFP(((BASE) + 1) & 7, af_a, 1, 3)           \
    STG(xb + m0g * K_DIM + kA, sAs);                                              \
    MFP(((BASE) + 2) & 7, af_b, 0, 2) MFP(((BASE) + 3) & 7, af_b, 1, 2)           \
    MFP(((BASE) + 2) & 7, af_b, 0, 3) MFP(((BASE) + 3) & 7, af_b, 1, 3)           \
    RD_A2(af_a, ((BASE) + 4) & 7, sAr);                                           \
    STG(xb + (m0g + 128) * K_DIM + kA, sAs + 16384);                              \
    MFP(((BASE) + 2) & 7, af_b, 0, 0) MFP(((BASE) + 3) & 7, af_b, 1, 0)           \
    MFP(((BASE) + 2) & 7, af_b, 0, 1) MFP(((BASE) + 3) & 7, af_b, 1, 1)           \
    MFP(((BASE) + 4) & 7, af_a, 0, 0) MFP(((BASE) + 5) & 7, af_a, 1, 0)           \
    MFP(((BASE) + 4) & 7, af_a, 0, 1) MFP(((BASE) + 5) & 7, af_a, 1, 1)           \
    RD_A2(af_b, ((BASE) + 6) & 7, sAr);                                           \
    MFP(((BASE) + 4) & 7, af_a, 0, 2) MFP(((BASE) + 5) & 7, af_a, 1, 2)           \
    MFP(((BASE) + 4) & 7, af_a, 0, 3) MFP(((BASE) + 5) & 7, af_a, 1, 3)           \
    MFP(((BASE) + 6) & 7, af_b, 0, 2) MFP(((BASE) + 7) & 7, af_b, 1, 2)           \
    MFP(((BASE) + 6) & 7, af_b, 0, 3) MFP(((BASE) + 7) & 7, af_b, 1, 3)           \
    MFP(((BASE) + 6) & 7, af_b, 0, 0) MFP(((BASE) + 7) & 7, af_b, 1, 0)           \
    MFP(((BASE) + 6) & 7, af_b, 0, 1) MFP(((BASE) + 7) & 7, af_b, 1, 1)           \
    __builtin_amdgcn_s_setprio(0);

#define TILE_SETUP                                                                \
    const int cur = t & 1;                                                        \
    const int cB = 98304 + cur * 32768;                                           \
    const int nB = 98304 + (cur ^ 1) * 32768;                                     \
    const long kB = (long)((t + 1 < KSTEPS ? t + 1 : KSTEPS - 1) * 64);           \
    const long kA = (long)((t + 2 < KSTEPS ? t + 2 : KSTEPS - 1) * 64);

#define TILE_BOUND                                                                \
    asm volatile("s_waitcnt vmcnt(4)");                                           \
    __builtin_amdgcn_sched_barrier(0);                                            \
    __builtin_amdgcn_s_barrier();                                                 \
    __builtin_amdgcn_sched_barrier(0);                                            \
    int tmp = sAr; sAr = sAn; sAn = sAs; sAs = tmp;

__global__ __launch_bounds__(512, 2) void gemm_pipe(
    const unsigned short* __restrict__ xb, const unsigned short* __restrict__ wb,
    float* __restrict__ C) {
  __align__(16) __shared__ unsigned char LDSbuf[163840];   // 96K A(3) + 64K B(2)

  const int tid = threadIdx.x;
  const int wid = tid >> 6, lane = tid & 63;
  const int wr = wid >> 2, wc = wid & 3;
  const int r16 = lane & 15, hi = lane >> 4;

  // ---- supertile mapping: 8mb x 4nb concurrent per XCD (R7-proven) ----
  const int p = ((int)blockIdx.x & 7) * (NWG / 8) + ((int)blockIdx.x >> 3);
  int mb, nb;
  if (p < 1280) {                 // 10 full nbg x 4 mbg x 32
    const int nbg = p >> 7;
    const int rem = p & 127;
    const int mbg = rem >> 5;
    const int s   = rem & 31;
    mb = mbg * 8 + (s & 7);
    nb = nbg * 4 + (s >> 3);
  } else {                        // ragged tail: nb 40..42, 4 mbg x 24
    const int q   = p - 1280;
    const int mbg = q / 24;
    const int s   = q % 24;
    mb = mbg * 8 + (s & 7);
    nb = 40 + (s >> 3);
  }
  const long m0g = (long)mb * BM, n0g = (long)nb * BN;

  // staging coords (per lane); T2: linear LDS dest, inverse-swizzled source
  const int srow = wid * 8 + (lane >> 3);
  const int scol = ((lane & 7) ^ (lane >> 3)) * 8;

  // ds_read coords (T2 swizzle on read)
  const int aoff = (wr * 128 + r16) * 128;
  const int boff = (wc * 64 + r16) * 128;
  const int kswz0 = ((hi ^ (r16 & 7)) << 4);
  const int kswz1 = kswz0 ^ 64;

  // ---- prologue: A(0)->slot0, B(0)->par0, A(1)->slot1; wait all but A(1) ----
  STG(xb + m0g * K_DIM,              0);
  STG(xb + (m0g + 128) * K_DIM,      16384);
  STG(wb + n0g * K_DIM,              98304);
  STG(wb + (n0g + 128) * K_DIM,      98304 + 16384);
  STG(xb + m0g * K_DIM + 64,         32768);
  STG(xb + (m0g + 128) * K_DIM + 64, 32768 + 16384);
  asm volatile("s_waitcnt vmcnt(4)");
  __builtin_amdgcn_sched_barrier(0);
  __builtin_amdgcn_s_barrier();

  bf16x8 af_a[2][2], af_b[2][2], bq[4][2];
  f32x4 acc[8][4] = {};

  int sAr = 0, sAn = 32768, sAs = 65536;   // A slots: read(t), read(t+1), stage(t+2)

  if ((wid & 1) == 0) {
    for (int t = 0; t < KSTEPS; ++t) {
      TILE_SETUP
      TILE_BODY(0)
      TILE_BOUND
    }
  } else {
    for (int t = 0; t < KSTEPS; ++t) {
      TILE_SETUP
      TILE_BODY(4)
      TILE_BOUND
    }
  }

  // ---- epilogue: C/D layout col=lane&15, row=hi*4+reg; nontemporal ----
  const long crow = m0g + wr * 128 + hi * 4;
  const long ccol = n0g + wc * 64 + r16;
#pragma unroll
  for (int m = 0; m < 8; ++m)
#pragma unroll
    for (int n = 0; n < 4; ++n)
#pragma unroll
      for (int r = 0; r < 4; ++r)
        __builtin_nontemporal_store(
            acc[m][n][r], &C[(crow + m * 16 + r) * N_DIM + ccol + n * 16]);
}

// ---------------- fallback (no workspace): fused 128^2 kernel ----------------
__global__ __launch_bounds__(256) void gemm_fallback(
    const float* __restrict__ Xf, const int* __restrict__ qw,
    const int* __restrict__ qs, const float* __restrict__ qf,
    const float* __restrict__ meanp, float* __restrict__ C) {
  __shared__ unsigned short As[128 * 64];
  __shared__ unsigned short Bs[128 * 64];
  __shared__ float tbl[16];
  const int tid = threadIdx.x;
  if (tid < 16) tbl[tid] = NF4_TBL[tid];
  const float mu = meanp[0];
  const int nwg = (M_ROWS / 128) * (N_DIM / 128);
  const int wg = ((int)blockIdx.x & 7) * (nwg / 8) + ((int)blockIdx.x >> 3);
  const int mbf = wg % (M_ROWS / 128), nbf = wg / (M_ROWS / 128);
  const int m0 = mbf * 128, n0 = nbf * 128;
  const int wid = tid >> 6, lane = tid & 63;
  const int wrf = wid >> 1, wcc = wid & 1;
  const int r16 = lane & 15, hi = lane >> 4;
  f32x4 acc[4][4] = {};
  for (int t = 0; t < KSTEPS; ++t) {
    const int k0 = t * 64;
    __syncthreads();
#pragma unroll
    for (int i = 0; i < 4; ++i) {
      int gi = i * 256 + tid;
      int row = gi >> 3, kq = (gi & 7) * 8;
      const float* px = Xf + (long)(m0 + row) * K_DIM + k0 + kq;
      f32x4 v0 = *(const f32x4*)px;
      f32x4 v1 = *(const f32x4*)(px + 4);
      u16x8 o;
      o[0] = f2bf(v0[0]); o[1] = f2bf(v0[1]); o[2] = f2bf(v0[2]); o[3] = f2bf(v0[3]);
      o[4] = f2bf(v1[0]); o[5] = f2bf(v1[1]); o[6] = f2bf(v1[2]); o[7] = f2bf(v1[3]);
      *(u16x8*)&As[row * 64 + kq] = o;
    }
#pragma unroll
    for (int i = 0; i < 4; ++i) {
      int gi = i * 256 + tid;
      int row = gi >> 3, kq = (gi & 7) * 8;
      const int* pq = qw + (long)(n0 + row) * K_DIM + k0 + kq;
      i32x4 q0 = *(const i32x4*)pq;
      i32x4 q1 = *(const i32x4*)(pq + 4);
      int g = (n0 + row) * (K_DIM / 64) + t;
      float s = (float)qs[g] / qf[g >> 8] + mu;
      u16x8 o;
      o[0] = f2bf(tbl[q0[0]] * s); o[1] = f2bf(tbl[q0[1]] * s);
      o[2] = f2bf(tbl[q0[2]] * s); o[3] = f2bf(tbl[q0[3]] * s);
      o[4] = f2bf(tbl[q1[0]] * s); o[5] = f2bf(tbl[q1[1]] * s);
      o[6] = f2bf(tbl[q1[2]] * s); o[7] = f2bf(tbl[q1[3]] * s);
      *(u16x8*)&Bs[row * 64 + kq] = o;
    }
    __syncthreads();
    bf16x8 afr[4][2], bfr[4][2];
#pragma unroll
    for (int i = 0; i < 4; ++i)
#pragma unroll
      for (int h = 0; h < 2; ++h) {
        afr[i][h] = *(const bf16x8*)&As[(wrf * 64 + i * 16 + r16) * 64 + h * 32 + hi * 8];
        bfr[i][h] = *(const bf16x8*)&Bs[(wcc * 64 + i * 16 + r16) * 64 + h * 32 + hi * 8];
      }
#pragma unroll
    for (int i = 0; i < 4; ++i)
#pragma unroll
      for (int j = 0; j < 4; ++j) {
        acc[i][j] = __builtin_amdgcn_mfma_f32_16x16x32_bf16(afr[i][0], bfr[j][0], acc[i][j], 0, 0, 0);
        acc[i][j] = __builtin_amdgcn_mfma_f32_16x16x32_bf16(afr[i][1], bfr[j][1], acc[i][j], 0, 0, 0);
      }
  }
  const int crow = m0 + wrf * 64 + hi * 4;
  const int ccol = n0 + wcc * 64 + r16;
#pragma unroll
  for (int i = 0; i < 4; ++i)
#pragma unroll
    for (int j = 0; j < 4; ++j)
#pragma unroll
      for (int r = 0; r < 4; ++r)
        C[(long)(crow + i * 16 + r) * N_DIM + (ccol + j * 16)] = acc[i][j][r];
}

extern "C" void kernel_launch(void* const* d_in, const int* in_sizes, int n_in,
                              void* d_out, int out_size, void* d_ws, size_t ws_size,
                              hipStream_t stream) {
  const float* x    = (const float*)d_in[0];
  const int*   qw   = (const int*)d_in[1];
  const int*   qs   = (const int*)d_in[2];
  const float* qf   = (const float*)d_in[3];
  const float* mean = (const float*)d_in[4];
  float* out = (float*)d_out;

  const size_t xb_bytes = (size_t)M_ROWS * K_DIM * 2;  // 64 MiB
  const size_t wb_bytes = (size_t)N_DIM * K_DIM * 2;   // 86 MiB

  if (ws_size >= xb_bytes + wb_bytes) {
    unsigned short* xb = (unsigned short*)d_ws;
    unsigned short* wb = (unsigned short*)((char*)d_ws + xb_bytes);
    convert_x_kernel<<<4096, 256, 0, stream>>>(x, xb);
    dequant_w_kernel<<<4096, 256, 0, stream>>>(qw, qs, qf, mean, wb);
    gemm_pipe<<<NWG, 512, 0, stream>>>(xb, wb, out);
  } else {
    gemm_fallback<<<(M_ROWS / 128) * (N_DIM / 128), 256, 0, stream>>>(
        x, qw, qs, qf, mean, out);
  }
}